// Round 2
// baseline (341.275 us; speedup 1.0000x reference)
//
#include <hip/hip_runtime.h>

#define NBINS 50
#define PAD_G 100
#define TPB 256
#define GRID 2048   // 8 blocks/CU on 256 CUs -> 32 waves/CU resident

typedef float vf4 __attribute__((ext_vector_type(4)));

// Gaussian kernel (5 taps, sigma=0.5), normalized
#define K0 2.6387004e-4f
#define K1 1.0645079e-1f
#define K2 7.8657085e-1f

__device__ __forceinline__ int quant(int g) {
  int d = g - 50;
  d = (d < 0) ? 0 : d;
  int q = __umul24((unsigned)d, 10923u) >> 16;  // exact /6 for this range
  return (q > NBINS - 1) ? (NBINS - 1) : q;
}

__device__ __forceinline__ float softplus_stable(float x) {
  return fmaxf(x, 0.f) + __logf(1.f + __expf(-fabsf(x)));
}

// qv2[f]: low byte = code(frame f), high byte = code(frame f+1); 255 = padded.
// Also accumulates #non-pad frames into acc[1] (mask.sum() == 50 * that).
__global__ __launch_bounds__(256) void pitch_pre(
    const int* __restrict__ gt, unsigned short* __restrict__ qv2, int n,
    float* __restrict__ acc)
{
  const int f = blockIdx.x * blockDim.x + threadIdx.x;
  if (f >= n) return;
  const int g0 = gt[f];
  const int f1 = (f + 1 < n) ? f + 1 : n - 1;
  const int g1 = gt[f1];
  const unsigned b0 = (g0 == PAD_G) ? 255u : (unsigned)quant(g0);
  const unsigned b1 = (g1 == PAD_G) ? 255u : (unsigned)quant(g1);
  qv2[f] = (unsigned short)(b0 | (b1 << 8));
  const unsigned long long ball = __ballot(g0 != PAD_G);
  if ((threadIdx.x & 63) == 0)
    atomicAdd((unsigned*)&acc[1], (unsigned)__popcll(ball));
}

// s_tab layout: 51 rows x 8 cols. Row q (q<50): col d1 holds the blur weight
// for output bin j = q - 2 + (d1-1); cols 0,6,7 are zero. Row 50 is all zero
// (absorbs pad code 255). Lookup index: clamp(j - c + 3, 0, 7) -- no extra
// range compare needed, out-of-range taps land on zero entries.
__device__ __forceinline__ void consume_chunk(
    vf4 p, unsigned q2, int j0, const float* s_tab, float& num)
{
  const unsigned c0 = q2 & 255u;
  const unsigned c1 = q2 >> 8;
#pragma unroll
  for (int u = 0; u < 4; ++u) {
    int j = j0 + u;
    const bool wrap = (j >= NBINS);
    const unsigned c = wrap ? c1 : c0;
    j = wrap ? j - NBINS : j;
    const float x = p[u];
    const float sp = softplus_stable(x);
    const unsigned qc = (c > 50u) ? 50u : c;   // 255 -> zero row
    int dj = j - (int)c + 3;                   // tap offset +2, bias +1
    dj = dj < 0 ? 0 : (dj > 7 ? 7 : dj);
    const float t = s_tab[(qc << 3) + dj];
    const float spv = (c != 255u) ? sp : 0.f;  // pad frames contribute nothing
    num += __builtin_fmaf(-x, t, spv);
  }
}

__global__ __launch_bounds__(TPB, 8) void pitch_loss_main(
    const vf4* __restrict__ preds4,
    const unsigned short* __restrict__ qv2,
    int nvec, int total, int nblocks,
    float* __restrict__ acc,     // [0]=num(float) [1]=nvalid(uint) [2]=ctr(uint)
    float* __restrict__ out)
{
  __shared__ float s_tab[51 * 8];
  for (int idx = threadIdx.x; idx < 51 * 8; idx += TPB) {
    const int q = idx >> 3;
    const int dt = (idx & 7) - 1;        // tap offset in [-1..6]; valid 0..4
    float t = 0.f;
    if (q < NBINS && 0 <= dt && dt < 5) {
      const int j = q - 2 + dt;
      if (0 <= j && j < NBINS) {
        const float kk[5] = {K0, K1, K2, K1, K0};
#pragma unroll
        for (int i = 0; i < 5; ++i) {
          int m = j - 2 + i;
          m = (m < 0) ? -m : m;
          m = (m > NBINS - 1) ? 2 * (NBINS - 1) - m : m;
          if (m == q) t += kk[i];
        }
      }
    }
    s_tab[idx] = t;
  }
  __syncthreads();

  const int tid = blockIdx.x * TPB + threadIdx.x;
  const int nthreads = nblocks * TPB;
  float num = 0.f;

  // Bulk: grid-stride, unroll-by-4 (4 independent b128 loads in flight per
  // wave; 8 waves/SIMD TLP does the rest of the latency hiding). Plain cached
  // loads: the 105 MB input is Infinity-Cache resident across iterations --
  // the old nontemporal hint was forcing half the reads to HBM every pass.
  const int iters = nvec / nthreads;     // 12 for 6,553,600 / 524,288
  int v = tid;
  int i = 0;
  for (; i + 4 <= iters; i += 4) {
    const int va = v;
    const int vb = v + nthreads;
    const int vc = v + 2 * nthreads;
    const int vd = v + 3 * nthreads;
    const vf4 pa = preds4[va];
    const vf4 pb = preds4[vb];
    const vf4 pc = preds4[vc];
    const vf4 pd = preds4[vd];
    const int ea = va << 2, eb = vb << 2, ec = vc << 2, ed = vd << 2;
    const unsigned fa = (unsigned)ea / 50u;
    const unsigned fb = (unsigned)eb / 50u;
    const unsigned fc = (unsigned)ec / 50u;
    const unsigned fd = (unsigned)ed / 50u;
    const unsigned qa = qv2[fa];
    const unsigned qb = qv2[fb];
    const unsigned qcv = qv2[fc];
    const unsigned qd = qv2[fd];
    consume_chunk(pa, qa,  ea - (int)fa * 50, s_tab, num);
    consume_chunk(pb, qb,  eb - (int)fb * 50, s_tab, num);
    consume_chunk(pc, qcv, ec - (int)fc * 50, s_tab, num);
    consume_chunk(pd, qd,  ed - (int)fd * 50, s_tab, num);
    v += 4 * nthreads;
  }
  for (; i < iters; ++i) {
    const vf4 p = preds4[v];
    const int e = v << 2;
    const unsigned f = (unsigned)e / 50u;
    consume_chunk(p, qv2[f], e - (int)f * 50, s_tab, num);
    v += nthreads;
  }
  // vector remainder (262,144 chunks at this shape: tid < 262,144 do one more)
  for (int vv = iters * nthreads + tid; vv < nvec; vv += nthreads) {
    const vf4 p = preds4[vv];
    const int e = vv << 2;
    const unsigned f = (unsigned)e / 50u;
    consume_chunk(p, qv2[f], e - (int)f * 50, s_tab, num);
  }
  // scalar element tail (total % 4 != 0; empty at this shape)
  for (int e = (nvec << 2) + tid; e < total; e += nthreads) {
    const unsigned f = (unsigned)e / 50u;
    const int j = e - (int)f * 50;
    const unsigned c = qv2[f] & 255u;
    const float x = ((const float*)preds4)[e];
    const unsigned qc = (c > 50u) ? 50u : c;
    int dj = j - (int)c + 3;
    dj = dj < 0 ? 0 : (dj > 7 ? 7 : dj);
    const float t = s_tab[(qc << 3) + dj];
    const float spv = (c != 255u) ? softplus_stable(x) : 0.f;
    num += __builtin_fmaf(-x, t, spv);
  }

  // wave-64 reduction, then one atomic per block
  const int wave = threadIdx.x >> 6;
  const int lane = threadIdx.x & 63;
#pragma unroll
  for (int off = 32; off > 0; off >>= 1)
    num += __shfl_down(num, off, 64);
  __shared__ float sn[TPB / 64];
  if (lane == 0) sn[wave] = num;
  __syncthreads();
  if (threadIdx.x == 0) {
    const float n = sn[0] + sn[1] + sn[2] + sn[3];
    atomicAdd(&acc[0], n);
    __threadfence();
    const unsigned done = atomicAdd((unsigned*)&acc[2], 1u);
    if (done == (unsigned)nblocks - 1u) {
      const float tn = atomicAdd(&acc[0], 0.f);
      const unsigned nvalid = atomicAdd((unsigned*)&acc[1], 0u);
      out[0] = tn / (50.0f * (float)nvalid);
    }
  }
}

extern "C" void kernel_launch(void* const* d_in, const int* in_sizes, int n_in,
                              void* d_out, int out_size, void* d_ws, size_t ws_size,
                              hipStream_t stream) {
  const vf4* preds4 = (const vf4*)d_in[0];
  const int* gt = (const int*)d_in[1];
  float* out = (float*)d_out;
  float* acc = (float*)d_ws;                                   // 12 B
  unsigned short* qv2 = (unsigned short*)((char*)d_ws + 256);  // 1 MB
  const int total = in_sizes[0];     // 26214400
  const int nframes = in_sizes[1];   // 524288
  const int nvec = total >> 2;       // 6553600

  (void)hipMemsetAsync(acc, 0, 3 * sizeof(float), stream);

  pitch_pre<<<(nframes + 255) / 256, 256, 0, stream>>>(gt, qv2, nframes, acc);

  pitch_loss_main<<<GRID, TPB, 0, stream>>>(
      preds4, qv2, nvec, total, GRID, acc, out);
}